// Round 12
// baseline (67.082 us; speedup 1.0000x reference)
//
#include <hip/hip_runtime.h>
#include <math.h>

constexpr int kD   = 128;
constexpr int kE   = 256;
constexpr int kTok = 2048;

// CALIBRATION ROUND: identical R11 pipeline launched TWICE (6 nodes).
// All kernels idempotent -> output identical; the marginal cost of the
// second (L2-warm) pipeline measures per-node overhead + warm kernel time.

// ---------------- K1: gate, 8 tokens/block ----------------------------------
__global__ __launch_bounds__(1024) void k_gate8(
    const float* __restrict__ x, const float* __restrict__ gate_w,
    const float* __restrict__ gate_b,
    float2* __restrict__ tokinfo, int* __restrict__ top2)
{
    const int b  = blockIdx.x;
    const int t  = threadIdx.x;
    const int ge = t & 255;
    const int tg = t >> 8;          // 0..3
    const int ln = t & 63;
    const int wg = (t >> 6) & 3;    // wave within token-group
    const int tok0 = b * 8;
    const int j0 = tg * 2, j1 = tg * 2 + 1;

    __shared__ float xsT[kD][10];
    __shared__ float partf[8][4];
    __shared__ int   parti[8][4];
    __shared__ float pv0s[8];
    __shared__ int   pi0s[8];

    {
        const int row = t >> 7, d = t & 127;
        xsT[d][row] = x[(size_t)(tok0 + row) * kD + d];
    }
    __syncthreads();

    const float bias = gate_b[ge];
    float lg0 = bias, lg1 = bias;
    #pragma unroll 8
    for (int d = 0; d < kD; ++d) {
        const float w = gate_w[d * kE + ge];
        const float2 xv = *(const float2*)&xsT[d][tg * 2];
        lg0 = fmaf(xv.x, w, lg0);
        lg1 = fmaf(xv.y, w, lg1);
    }

    float m0 = lg0, m1 = lg1;
    #pragma unroll
    for (int s = 1; s < 64; s <<= 1) {
        m0 = fmaxf(m0, __shfl_xor(m0, s));
        m1 = fmaxf(m1, __shfl_xor(m1, s));
    }
    if (ln == 0) { partf[j0][wg] = m0; partf[j1][wg] = m1; }
    __syncthreads();
    const float mx0 = fmaxf(fmaxf(partf[j0][0], partf[j0][1]),
                            fmaxf(partf[j0][2], partf[j0][3]));
    const float mx1 = fmaxf(fmaxf(partf[j1][0], partf[j1][1]),
                            fmaxf(partf[j1][2], partf[j1][3]));
    __syncthreads();

    const float ex0 = __expf(lg0 - mx0), ex1 = __expf(lg1 - mx1);
    float s0 = ex0, s1 = ex1;
    #pragma unroll
    for (int s = 1; s < 64; s <<= 1) {
        s0 += __shfl_xor(s0, s);
        s1 += __shfl_xor(s1, s);
    }
    if (ln == 0) { partf[j0][wg] = s0; partf[j1][wg] = s1; }
    __syncthreads();
    const float tot0 = partf[j0][0] + partf[j0][1] + partf[j0][2] + partf[j0][3];
    const float tot1 = partf[j1][0] + partf[j1][1] + partf[j1][2] + partf[j1][3];
    const float p0 = ex0 / tot0, p1 = ex1 / tot1;
    __syncthreads();

    float v0 = p0, v1 = p1; int ix0 = ge, ix1 = ge;
    #pragma unroll
    for (int s = 1; s < 64; s <<= 1) {
        const float o0 = __shfl_xor(v0, s); const int q0 = __shfl_xor(ix0, s);
        if (o0 > v0 || (o0 == v0 && q0 < ix0)) { v0 = o0; ix0 = q0; }
        const float o1 = __shfl_xor(v1, s); const int q1 = __shfl_xor(ix1, s);
        if (o1 > v1 || (o1 == v1 && q1 < ix1)) { v1 = o1; ix1 = q1; }
    }
    if (ln == 0) {
        partf[j0][wg] = v0; parti[j0][wg] = ix0;
        partf[j1][wg] = v1; parti[j1][wg] = ix1;
    }
    __syncthreads();
    if (t < 8) {
        float bv = partf[t][0]; int bi = parti[t][0];
        #pragma unroll
        for (int w = 1; w < 4; ++w) {
            const float ov = partf[t][w]; const int oi = parti[t][w];
            if (ov > bv || (ov == bv && oi < bi)) { bv = ov; bi = oi; }
        }
        pv0s[t] = bv; pi0s[t] = bi;
    }
    __syncthreads();

    v0 = (ge == pi0s[j0]) ? -INFINITY : p0; ix0 = ge;
    v1 = (ge == pi0s[j1]) ? -INFINITY : p1; ix1 = ge;
    #pragma unroll
    for (int s = 1; s < 64; s <<= 1) {
        const float o0 = __shfl_xor(v0, s); const int q0 = __shfl_xor(ix0, s);
        if (o0 > v0 || (o0 == v0 && q0 < ix0)) { v0 = o0; ix0 = q0; }
        const float o1 = __shfl_xor(v1, s); const int q1 = __shfl_xor(ix1, s);
        if (o1 > v1 || (o1 == v1 && q1 < ix1)) { v1 = o1; ix1 = q1; }
    }
    if (ln == 0) {
        partf[j0][wg] = v0; parti[j0][wg] = ix0;
        partf[j1][wg] = v1; parti[j1][wg] = ix1;
    }
    __syncthreads();
    if (t < 8) {
        float bv = partf[t][0]; int bi = parti[t][0];
        #pragma unroll
        for (int w = 1; w < 4; ++w) {
            const float ov = partf[t][w]; const int oi = parti[t][w];
            if (ov > bv || (ov == bv && oi < bi)) { bv = ov; bi = oi; }
        }
        const int tok = tok0 + t;
        const float va = pv0s[t], vb = bv;
        const float den = va + vb + 1e-6f;
        tokinfo[tok] = make_float2(va / den, vb / den);
        top2[tok] = pi0s[t] | (bi << 8);
    }
}

// ---------------- K2: expert-grouped matvecs, 4-entry register-blocked ------
__global__ __launch_bounds__(1024) void k_expert(
    const float* __restrict__ x, const float* __restrict__ expert_w,
    const int* __restrict__ top2, float* __restrict__ ybuf)
{
    const int e  = blockIdx.x >> 1;
    const int hf = blockIdx.x & 1;
    const int t  = threadIdx.x;

    __shared__ float W[kD][64];
    __shared__ float xs[64][kD];
    __shared__ int   llist[kTok];
    __shared__ int   lcount;

    if (t == 0) lcount = 0;
    __syncthreads();

    #pragma unroll
    for (int k = 0; k < 2; ++k) {
        const int i = k * 1024 + t;
        const int pk = top2[i];
        if ((pk & 255) == e)        llist[atomicAdd(&lcount, 1)] = i * 2;
        if (((pk >> 8) & 255) == e) llist[atomicAdd(&lcount, 1)] = i * 2 + 1;
    }

    {
        const float* Wg = expert_w + (size_t)e * kD * kD + hf * 64;
        #pragma unroll
        for (int k = 0; k < 2; ++k) {
            const int f  = k * 1024 + t;
            const int r  = f >> 4;
            const int c4 = (f & 15) * 4;
            *(float4*)&W[r][c4] = *(const float4*)&Wg[(size_t)r * kD + c4];
        }
    }
    __syncthreads();
    const int n = lcount;

    const int wv = t >> 6, ln = t & 63;
    for (int base = 0; base < n; base += 64) {
        const int m = min(64, n - base);
        for (int i = t; i < m * kD; i += 1024) {
            const int row = i >> 7, d = i & 127;
            const int ev = llist[base + row];
            xs[row][d] = x[(size_t)(ev >> 1) * kD + d];
        }
        __syncthreads();

        const int i0 = base + wv * 4;
        if (i0 < n) {
            const int r0 = wv * 4;
            const int cnt = min(4, n - i0);
            float a0 = 0.f, a1 = 0.f, a2 = 0.f, a3 = 0.f;
            #pragma unroll 8
            for (int d = 0; d < kD; ++d) {
                const float w = W[d][ln];
                a0 = fmaf(xs[r0 + 0][d], w, a0);
                a1 = fmaf(xs[r0 + 1][d], w, a1);
                a2 = fmaf(xs[r0 + 2][d], w, a2);
                a3 = fmaf(xs[r0 + 3][d], w, a3);
            }
            {
                const int ev0 = llist[i0];
                ybuf[((size_t)(ev0 >> 1) * 2 + (ev0 & 1)) * kD + hf * 64 + ln] = a0;
            }
            if (cnt > 1) {
                const int ev1 = llist[i0 + 1];
                ybuf[((size_t)(ev1 >> 1) * 2 + (ev1 & 1)) * kD + hf * 64 + ln] = a1;
            }
            if (cnt > 2) {
                const int ev2 = llist[i0 + 2];
                ybuf[((size_t)(ev2 >> 1) * 2 + (ev2 & 1)) * kD + hf * 64 + ln] = a2;
            }
            if (cnt > 3) {
                const int ev3 = llist[i0 + 3];
                ybuf[((size_t)(ev3 >> 1) * 2 + (ev3 & 1)) * kD + hf * 64 + ln] = a3;
            }
        }
        __syncthreads();
    }
}

// ---------------- K3: combine + SwiGLU + consensus, 8 tokens/block ----------
__global__ __launch_bounds__(1024) void k_swiglu8(
    const float* __restrict__ ybuf, const float2* __restrict__ tokinfo,
    const float* __restrict__ w1m, const float* __restrict__ b1,
    const float* __restrict__ w2m, const float* __restrict__ b2,
    float* __restrict__ out_avg, float* __restrict__ out_cons)
{
    const int b = blockIdx.x;
    const int t = threadIdx.x;
    const int tok0 = b * 8;

    __shared__ float  ys[8][2][kD];
    __shared__ float  wavT[kD][9];
    __shared__ float  vv[8][kD];
    __shared__ float  os[8][kD];
    __shared__ float2 ti[8];
    __shared__ float  cparts[8][2];

    if (t < 512)
        ((float4*)&ys[0][0][0])[t] =
            ((const float4*)&ybuf[(size_t)tok0 * 2 * kD])[t];
    if (t < 8) ti[t] = tokinfo[tok0 + t];
    __syncthreads();

    {
        const int j = t >> 7, o = t & 127;
        const float2 w = ti[j];
        wavT[o][j] = w.x * ys[j][0][o] + w.y * ys[j][1][o];
    }
    __syncthreads();

    const int h = t >> 9, rem = t & 511, jp = rem >> 7, o = rem & 127;
    const float* Wm = h ? w2m : w1m;
    const float bias = h ? b2[o] : b1[o];
    float a0 = bias, a1 = bias;
    #pragma unroll 8
    for (int d = 0; d < kD; ++d) {
        const float w = Wm[d * kD + o];
        a0 = fmaf(wavT[d][jp],     w, a0);
        a1 = fmaf(wavT[d][jp + 4], w, a1);
    }
    if (h) { vv[jp][o] = a0; vv[jp + 4][o] = a1; }
    __syncthreads();
    if (!h) {
        const float r0 = a0 * (1.f / (1.f + __expf(-a0))) * vv[jp][o];
        const float r1 = a1 * (1.f / (1.f + __expf(-a1))) * vv[jp + 4][o];
        os[jp][o] = r0;
        os[jp + 4][o] = r1;
        out_avg[(size_t)(tok0 + jp) * kD + o]     = r0;
        out_avg[(size_t)(tok0 + jp + 4) * kD + o] = r1;
    }
    __syncthreads();

    {
        const int wv = t >> 6, ln = t & 63;
        const int tk = wv >> 1;
        const int o2 = (wv & 1) * 64 + ln;
        const float2 w = ti[tk];
        const float ot = os[tk][o2];
        const float d0 = ys[tk][0][o2] - ot;
        const float d1 = ys[tk][1][o2] - ot;
        float s = w.x * d0 * d0 + w.y * d1 * d1;
        #pragma unroll
        for (int sft = 1; sft < 64; sft <<= 1) s += __shfl_xor(s, sft);
        if (ln == 0) cparts[tk][wv & 1] = s;
    }
    __syncthreads();
    if (t < 8)
        out_cons[tok0 + t] = __expf(-(cparts[t][0] + cparts[t][1]) * (1.0f / (float)kD));
}

extern "C" void kernel_launch(void* const* d_in, const int* in_sizes, int n_in,
                              void* d_out, int out_size, void* d_ws, size_t ws_size,
                              hipStream_t stream) {
    const float*  x        = (const float*)d_in[0];
    const float*  gate_w   = (const float*)d_in[1];
    const float*  gate_b   = (const float*)d_in[2];
    const float*  expert_w = (const float*)d_in[3];
    const float*  w1m      = (const float*)d_in[4];
    const float*  b1       = (const float*)d_in[5];
    const float*  w2m      = (const float*)d_in[6];
    const float*  b2       = (const float*)d_in[7];

    float* out_avg  = (float*)d_out;
    float* out_cons = out_avg + (size_t)kTok * kD;

    char*   ws      = (char*)d_ws;
    float2* tokinfo = (float2*)ws;                 // 16 KB
    int*    top2    = (int*)(ws + 16384);          // 8 KB
    float*  ybuf    = (float*)(ws + 32768);        // 2 MB

    // pipeline #1 (cold)
    k_gate8  <<<kTok / 8, 1024, 0, stream>>>(x, gate_w, gate_b, tokinfo, top2);
    k_expert <<<kE * 2,   1024, 0, stream>>>(x, expert_w, top2, ybuf);
    k_swiglu8<<<kTok / 8, 1024, 0, stream>>>(ybuf, tokinfo, w1m, b1, w2m, b2, out_avg, out_cons);
    // pipeline #2 (warm, idempotent) -- measures marginal node cost
    k_gate8  <<<kTok / 8, 1024, 0, stream>>>(x, gate_w, gate_b, tokinfo, top2);
    k_expert <<<kE * 2,   1024, 0, stream>>>(x, expert_w, top2, ybuf);
    k_swiglu8<<<kTok / 8, 1024, 0, stream>>>(ybuf, tokinfo, w1m, b1, w2m, b2, out_avg, out_cons);
}

// Round 13
// 34.955 us; speedup vs baseline: 1.9191x; 1.9191x over previous
//
#include <hip/hip_runtime.h>
#include <math.h>

constexpr int kD   = 128;
constexpr int kE   = 256;
constexpr int kTok = 2048;

// FINAL (R10-proven, best measured 35.05 us):
//   3-node pipeline; expert-grouped K2 (compulsory weight traffic only);
//   structural floor = 3 x ~7us node boundary + ~14us latency-bound compute.
//   Measured dead ends: 1-node token-grouped (L2-fill-bound, 43-47us),
//   grid-barrier fusion (+80us, R4), cross-XCD coherent stores (+90us, R8).

// ---------------- K1: gate (logits -> softmax -> top2) ----------------------
__global__ __launch_bounds__(256) void k_gate(
    const float* __restrict__ x, const float* __restrict__ gate_w,
    const float* __restrict__ gate_b,
    float2* __restrict__ tokinfo, int* __restrict__ top2)
{
    const int b  = blockIdx.x;
    const int t  = threadIdx.x;
    const int wv = t >> 6, ln = t & 63;

    __shared__ float xsT[kD][4];
    __shared__ float partf[4][4];
    __shared__ int   parti[4][4];
    __shared__ int   pi0s[4];
    __shared__ float pv0s[4];

    {
        const float2 v = *(const float2*)(x + ((size_t)(b * 4 + wv)) * kD + ln * 2);
        xsT[ln * 2 + 0][wv] = v.x;
        xsT[ln * 2 + 1][wv] = v.y;
    }
    __syncthreads();

    float lg[4];
    {
        const float bias = gate_b[t];
        lg[0] = lg[1] = lg[2] = lg[3] = bias;
    }
    #pragma unroll 8
    for (int d = 0; d < kD; ++d) {
        const float w = gate_w[d * kE + t];
        const float4 xv = *(const float4*)&xsT[d][0];
        lg[0] = fmaf(xv.x, w, lg[0]);
        lg[1] = fmaf(xv.y, w, lg[1]);
        lg[2] = fmaf(xv.z, w, lg[2]);
        lg[3] = fmaf(xv.w, w, lg[3]);
    }

    // max over experts
    float m[4];
    #pragma unroll
    for (int j = 0; j < 4; ++j) m[j] = lg[j];
    #pragma unroll
    for (int s = 1; s < 64; s <<= 1) {
        #pragma unroll
        for (int j = 0; j < 4; ++j) m[j] = fmaxf(m[j], __shfl_xor(m[j], s));
    }
    if (ln == 0) {
        #pragma unroll
        for (int j = 0; j < 4; ++j) partf[wv][j] = m[j];
    }
    __syncthreads();
    float mx[4];
    #pragma unroll
    for (int j = 0; j < 4; ++j)
        mx[j] = fmaxf(fmaxf(partf[0][j], partf[1][j]), fmaxf(partf[2][j], partf[3][j]));
    __syncthreads();

    // sum of exp
    float ex[4], sm[4];
    #pragma unroll
    for (int j = 0; j < 4; ++j) { ex[j] = __expf(lg[j] - mx[j]); sm[j] = ex[j]; }
    #pragma unroll
    for (int s = 1; s < 64; s <<= 1) {
        #pragma unroll
        for (int j = 0; j < 4; ++j) sm[j] += __shfl_xor(sm[j], s);
    }
    if (ln == 0) {
        #pragma unroll
        for (int j = 0; j < 4; ++j) partf[wv][j] = sm[j];
    }
    __syncthreads();
    float p[4];
    #pragma unroll
    for (int j = 0; j < 4; ++j) {
        const float tot = partf[0][j] + partf[1][j] + partf[2][j] + partf[3][j];
        p[j] = ex[j] / tot;
    }
    __syncthreads();

    // argmax pass 1 (ties -> lower index)
    float v[4]; int ix[4];
    #pragma unroll
    for (int j = 0; j < 4; ++j) { v[j] = p[j]; ix[j] = t; }
    #pragma unroll
    for (int s = 1; s < 64; s <<= 1) {
        #pragma unroll
        for (int j = 0; j < 4; ++j) {
            const float ov = __shfl_xor(v[j], s);
            const int   oi = __shfl_xor(ix[j], s);
            if (ov > v[j] || (ov == v[j] && oi < ix[j])) { v[j] = ov; ix[j] = oi; }
        }
    }
    if (ln == 0) {
        #pragma unroll
        for (int j = 0; j < 4; ++j) { partf[wv][j] = v[j]; parti[wv][j] = ix[j]; }
    }
    __syncthreads();
    if (t < 4) {
        const int j = t;
        float bv = partf[0][j]; int bi = parti[0][j];
        #pragma unroll
        for (int w = 1; w < 4; ++w) {
            const float ov = partf[w][j]; const int oi = parti[w][j];
            if (ov > bv || (ov == bv && oi < bi)) { bv = ov; bi = oi; }
        }
        pv0s[j] = bv; pi0s[j] = bi;
    }
    __syncthreads();

    // argmax pass 2 (mask winner)
    #pragma unroll
    for (int j = 0; j < 4; ++j) {
        v[j] = (t == pi0s[j]) ? -INFINITY : p[j];
        ix[j] = t;
    }
    #pragma unroll
    for (int s = 1; s < 64; s <<= 1) {
        #pragma unroll
        for (int j = 0; j < 4; ++j) {
            const float ov = __shfl_xor(v[j], s);
            const int   oi = __shfl_xor(ix[j], s);
            if (ov > v[j] || (ov == v[j] && oi < ix[j])) { v[j] = ov; ix[j] = oi; }
        }
    }
    if (ln == 0) {
        #pragma unroll
        for (int j = 0; j < 4; ++j) { partf[wv][j] = v[j]; parti[wv][j] = ix[j]; }
    }
    __syncthreads();
    if (t < 4) {
        const int j = t;
        float bv = partf[0][j]; int bi = parti[0][j];
        #pragma unroll
        for (int w = 1; w < 4; ++w) {
            const float ov = partf[w][j]; const int oi = parti[w][j];
            if (ov > bv || (ov == bv && oi < bi)) { bv = ov; bi = oi; }
        }
        const int tok = b * 4 + j;
        const float v0 = pv0s[j], v1 = bv;
        const float den = v0 + v1 + 1e-6f;
        tokinfo[tok] = make_float2(v0 / den, v1 / den);
        top2[tok] = pi0s[j] | (bi << 8);
    }
}

// ---------------- K2: expert-grouped matvecs, 4-entry register-blocked ------
__global__ __launch_bounds__(1024) void k_expert(
    const float* __restrict__ x, const float* __restrict__ expert_w,
    const int* __restrict__ top2, float* __restrict__ ybuf)
{
    const int e  = blockIdx.x >> 1;
    const int hf = blockIdx.x & 1;
    const int t  = threadIdx.x;

    __shared__ float W[kD][64];    // 32 KB
    __shared__ float xs[64][kD];   // 32 KB
    __shared__ int   llist[kTok];  // 8 KB
    __shared__ int   lcount;

    if (t == 0) lcount = 0;
    __syncthreads();

    #pragma unroll
    for (int k = 0; k < 2; ++k) {
        const int i = k * 1024 + t;
        const int pk = top2[i];
        if ((pk & 255) == e)        llist[atomicAdd(&lcount, 1)] = i * 2;
        if (((pk >> 8) & 255) == e) llist[atomicAdd(&lcount, 1)] = i * 2 + 1;
    }

    {
        const float* Wg = expert_w + (size_t)e * kD * kD + hf * 64;
        #pragma unroll
        for (int k = 0; k < 2; ++k) {
            const int f  = k * 1024 + t;
            const int r  = f >> 4;
            const int c4 = (f & 15) * 4;
            *(float4*)&W[r][c4] = *(const float4*)&Wg[(size_t)r * kD + c4];
        }
    }
    __syncthreads();
    const int n = lcount;

    const int wv = t >> 6, ln = t & 63;
    for (int base = 0; base < n; base += 64) {
        const int m = min(64, n - base);
        for (int i = t; i < m * kD; i += 1024) {
            const int row = i >> 7, d = i & 127;
            const int ev = llist[base + row];
            xs[row][d] = x[(size_t)(ev >> 1) * kD + d];
        }
        __syncthreads();

        const int i0 = base + wv * 4;
        if (i0 < n) {
            const int r0 = wv * 4;
            const int cnt = min(4, n - i0);
            float a0 = 0.f, a1 = 0.f, a2 = 0.f, a3 = 0.f;
            #pragma unroll 8
            for (int d = 0; d < kD; ++d) {
                const float w = W[d][ln];
                a0 = fmaf(xs[r0 + 0][d], w, a0);
                a1 = fmaf(xs[r0 + 1][d], w, a1);
                a2 = fmaf(xs[r0 + 2][d], w, a2);
                a3 = fmaf(xs[r0 + 3][d], w, a3);
            }
            {
                const int ev0 = llist[i0];
                ybuf[((size_t)(ev0 >> 1) * 2 + (ev0 & 1)) * kD + hf * 64 + ln] = a0;
            }
            if (cnt > 1) {
                const int ev1 = llist[i0 + 1];
                ybuf[((size_t)(ev1 >> 1) * 2 + (ev1 & 1)) * kD + hf * 64 + ln] = a1;
            }
            if (cnt > 2) {
                const int ev2 = llist[i0 + 2];
                ybuf[((size_t)(ev2 >> 1) * 2 + (ev2 & 1)) * kD + hf * 64 + ln] = a2;
            }
            if (cnt > 3) {
                const int ev3 = llist[i0 + 3];
                ybuf[((size_t)(ev3 >> 1) * 2 + (ev3 & 1)) * kD + hf * 64 + ln] = a3;
            }
        }
        __syncthreads();
    }
}

// ---------------- K3: combine + SwiGLU + consensus --------------------------
__global__ __launch_bounds__(256) void k_swiglu(
    const float* __restrict__ ybuf, const float2* __restrict__ tokinfo,
    const float* __restrict__ w1m, const float* __restrict__ b1,
    const float* __restrict__ w2m, const float* __restrict__ b2,
    float* __restrict__ out_avg, float* __restrict__ out_cons)
{
    const int b = blockIdx.x;
    const int t = threadIdx.x;
    const int tok0 = b * 4;

    __shared__ float  ys[4 * 2 * kD];
    __shared__ float  wvT[kD][4];
    __shared__ float  vv[4][kD];
    __shared__ float  os[4][kD];
    __shared__ float2 ti[4];

    *(float4*)&ys[t * 4] = *(const float4*)&ybuf[(size_t)tok0 * 2 * kD + t * 4];
    if (t < 4) ti[t] = tokinfo[tok0 + t];
    __syncthreads();

    #pragma unroll
    for (int k = 0; k < 2; ++k) {
        const int idx = t * 2 + k;
        const int j = idx >> 7, o = idx & 127;
        const float2 w = ti[j];
        wvT[o][j] = w.x * ys[(j * 2 + 0) * kD + o] + w.y * ys[(j * 2 + 1) * kD + o];
    }
    __syncthreads();

    const int h = t >> 7, o = t & 127;
    const float* Wm = h ? w2m : w1m;
    const float bias = h ? b2[o] : b1[o];
    float a0 = bias, a1 = bias, a2 = bias, a3 = bias;
    #pragma unroll 4
    for (int d = 0; d < kD; ++d) {
        const float w = Wm[d * kD + o];
        const float4 xv = *(const float4*)&wvT[d][0];
        a0 = fmaf(xv.x, w, a0);
        a1 = fmaf(xv.y, w, a1);
        a2 = fmaf(xv.z, w, a2);
        a3 = fmaf(xv.w, w, a3);
    }
    if (h) { vv[0][o] = a0; vv[1][o] = a1; vv[2][o] = a2; vv[3][o] = a3; }
    __syncthreads();
    if (!h) {
        float gg[4] = {a0, a1, a2, a3};
        #pragma unroll
        for (int j = 0; j < 4; ++j) {
            const float g = gg[j];
            const float r = g * (1.f / (1.f + __expf(-g))) * vv[j][o];
            os[j][o] = r;
            out_avg[(size_t)(tok0 + j) * kD + o] = r;
        }
    }
    __syncthreads();

    const int wv = t >> 6, ln = t & 63;
    const float2 w = ti[wv];
    float s = 0.f;
    #pragma unroll
    for (int k = 0; k < 2; ++k) {
        const int oo = ln * 2 + k;
        const float ot = os[wv][oo];
        const float d0 = ys[(wv * 2 + 0) * kD + oo] - ot;
        const float d1 = ys[(wv * 2 + 1) * kD + oo] - ot;
        s += w.x * d0 * d0 + w.y * d1 * d1;
    }
    #pragma unroll
    for (int sft = 1; sft < 64; sft <<= 1) s += __shfl_xor(s, sft);
    if (ln == 0) out_cons[tok0 + wv] = __expf(-s * (1.0f / (float)kD));
}

extern "C" void kernel_launch(void* const* d_in, const int* in_sizes, int n_in,
                              void* d_out, int out_size, void* d_ws, size_t ws_size,
                              hipStream_t stream) {
    const float*  x        = (const float*)d_in[0];
    const float*  gate_w   = (const float*)d_in[1];
    const float*  gate_b   = (const float*)d_in[2];
    const float*  expert_w = (const float*)d_in[3];
    const float*  w1m      = (const float*)d_in[4];
    const float*  b1       = (const float*)d_in[5];
    const float*  w2m      = (const float*)d_in[6];
    const float*  b2       = (const float*)d_in[7];

    float* out_avg  = (float*)d_out;
    float* out_cons = out_avg + (size_t)kTok * kD;

    char*   ws      = (char*)d_ws;
    float2* tokinfo = (float2*)ws;                 // 16 KB
    int*    top2    = (int*)(ws + 16384);          // 8 KB
    float*  ybuf    = (float*)(ws + 32768);        // 2 MB

    k_gate  <<<kTok / 4, 256,  0, stream>>>(x, gate_w, gate_b, tokinfo, top2);
    k_expert<<<kE * 2,   1024, 0, stream>>>(x, expert_w, top2, ybuf);
    k_swiglu<<<kTok / 4, 256,  0, stream>>>(ybuf, tokinfo, w1m, b1, w2m, b2, out_avg, out_cons);
}